// Round 9
// baseline (557.623 us; speedup 1.0000x reference)
//
#include <hip/hip_runtime.h>
#include <hip/hip_bf16.h>
#include <stdint.h>

// Problem constants
#define T_DIM 2048
#define B_DIM 8
#define D_DIM 1024
#define NSTATE 1024
#define BLKSZ 8
#define NB 128
#define M_DIM (T_DIM * B_DIM)   // 16384
#define N_DIM (3 * NSTATE)      // 3072 (k | v | q concatenated)
#define K_DIM D_DIM             // 1024

typedef __bf16 bf16x8 __attribute__((ext_vector_type(8)));
typedef float f32x4 __attribute__((ext_vector_type(4)));
typedef unsigned int uintx4 __attribute__((ext_vector_type(4)));

typedef __attribute__((address_space(3))) void lds_void;
typedef __attribute__((address_space(1))) const void glb_void;

__device__ __forceinline__ unsigned short f2bf(float f) {
  unsigned u = __float_as_uint(f);
  u = (u + 0x7FFFu + ((u >> 16) & 1u)) >> 16;  // RNE
  return (unsigned short)u;
}
// unpack bf16 #hi (0=low,1=high) from a packed u32, as float (1 VALU op)
__device__ __forceinline__ float bfu(unsigned r, int hi) {
  return __uint_as_float(hi ? (r & 0xFFFF0000u) : (r << 16));
}

__device__ __forceinline__ void load_lds16(const unsigned short* g,
                                           unsigned short* l) {
  __builtin_amdgcn_global_load_lds((glb_void*)g, (lds_void*)l, 16, 0, 0);
}

// DPP butterfly add (groups = physical lanes)
template <int CTRL>
__device__ __forceinline__ float dpp_add(float x) {
  int y = __builtin_amdgcn_update_dpp(0, __float_as_int(x), CTRL, 0xF, 0xF, true);
  return x + __int_as_float(y);
}
__device__ __forceinline__ float reduce8(float x) {
  x = dpp_add<0xB1>(x);   // quad_perm(1,0,3,2): lane ^ 1
  x = dpp_add<0x4E>(x);   // quad_perm(2,3,0,1): lane ^ 2
  x = dpp_add<0x141>(x);  // row_half_mirror: crosses quads within 8-group
  return x;
}

// ---------------- Kernel 1: fp32 -> bf16 conversion of x and Wcat ----------
__global__ __launch_bounds__(256) void convert_kernel(
    const float* __restrict__ x, const float* __restrict__ Wk,
    const float* __restrict__ Wv, const float* __restrict__ Wq,
    unsigned short* __restrict__ xb, unsigned short* __restrict__ wb) {
  size_t idx = (size_t)blockIdx.x * blockDim.x + threadIdx.x;
  size_t row = idx >> 8;
  int c4 = (int)(idx & 255) * 4;
  const float* src;
  unsigned short* dst;
  if (row < (size_t)M_DIM) {
    src = x + row * K_DIM;
    dst = xb + row * K_DIM;
  } else {
    size_t r = row - M_DIM;
    const float* w = (r < 1024) ? Wk : (r < 2048 ? Wv : Wq);
    src = w + (r & 1023) * K_DIM;
    dst = wb + r * K_DIM;
  }
  float4 v = *(const float4*)(src + c4);
  ushort4 o;
  o.x = f2bf(v.x); o.y = f2bf(v.y); o.z = f2bf(v.z); o.w = f2bf(v.w);
  *(ushort4*)(dst + c4) = o;
}

// ---------------- Kernel 2: bf16 MFMA GEMM, LDS-staged coalesced epilogue --
// (FROZEN from R7.) pk record per chain per tblk (192 ushorts):
//   [seg(k,v,q)][elem(j or i)][ut_store], ut_store = (t&1)*4 + ((t&7)>>1).
#define BM 128
#define BN 128
#define BK 32
#define C_PLANE 49152  // ushorts per chain (256 tblk * 192)

__global__ __launch_bounds__(256) void gemm_kernel(
    const unsigned short* __restrict__ A,     // [M][K] bf16
    const unsigned short* __restrict__ Bmat,  // [N][K] bf16
    unsigned short* __restrict__ pk) {        // packed, layout above
  // 32 KB: K-loop As[2]/Bs[2] dbuf, then reused as epilogue staging.
  __shared__ unsigned short smem[16384];

  const int tid = threadIdx.x;
  const int nTiles = N_DIM / BN;  // 24
  const int nTile = blockIdx.x % nTiles;
  const int mTile = blockIdx.x / nTiles;
  const int m0 = mTile * BM, n0 = nTile * BN;

  const int lane = tid & 63, wave = tid >> 6;
  const int wm = wave >> 1, wn = wave & 1;
  const int l15 = lane & 15, quad = lane >> 4;
  const int sw = quad ^ ((l15 >> 1) & 3);

  const int srow = lane >> 2;
  const int sblk = (lane & 3) ^ ((lane >> 3) & 3);
  const int c0 = wave, c1 = wave + 4;

  const unsigned short* gA0 = A + (size_t)(m0 + c0 * 16 + srow) * K_DIM + sblk * 8;
  const unsigned short* gA1 = A + (size_t)(m0 + c1 * 16 + srow) * K_DIM + sblk * 8;
  const unsigned short* gB0 = Bmat + (size_t)(n0 + c0 * 16 + srow) * K_DIM + sblk * 8;
  const unsigned short* gB1 = Bmat + (size_t)(n0 + c1 * 16 + srow) * K_DIM + sblk * 8;

  f32x4 acc[4][4];
#pragma unroll
  for (int mi = 0; mi < 4; mi++)
#pragma unroll
    for (int ni = 0; ni < 4; ni++) acc[mi][ni] = (f32x4){0.f, 0.f, 0.f, 0.f};

#define STAGE(KOFF, BUF)                                          \
  {                                                               \
    load_lds16(gA0 + (KOFF), smem + (BUF)*4096 + c0 * 512);       \
    load_lds16(gA1 + (KOFF), smem + (BUF)*4096 + c1 * 512);       \
    load_lds16(gB0 + (KOFF), smem + 8192 + (BUF)*4096 + c0 * 512);\
    load_lds16(gB1 + (KOFF), smem + 8192 + (BUF)*4096 + c1 * 512);\
  }

#define COMPUTE(BUF)                                                          \
  {                                                                           \
    bf16x8 af[4], bfr[4];                                                     \
    _Pragma("unroll") for (int mi = 0; mi < 4; mi++) {                        \
      uintx4 r = *(const uintx4*)(smem + (BUF)*4096 +                         \
                                  (wm * 64 + mi * 16 + l15) * BK + sw * 8);   \
      af[mi] = __builtin_bit_cast(bf16x8, r);                                 \
    }                                                                         \
    _Pragma("unroll") for (int ni = 0; ni < 4; ni++) {                        \
      uintx4 r = *(const uintx4*)(smem + 8192 + (BUF)*4096 +                  \
                                  (wn * 64 + ni * 16 + l15) * BK + sw * 8);   \
      bfr[ni] = __builtin_bit_cast(bf16x8, r);                                \
    }                                                                         \
    _Pragma("unroll") for (int mi = 0; mi < 4; mi++)                          \
        _Pragma("unroll") for (int ni = 0; ni < 4; ni++)                      \
            acc[mi][ni] = __builtin_amdgcn_mfma_f32_16x16x32_bf16(            \
                af[mi], bfr[ni], acc[mi][ni], 0, 0, 0);                       \
  }

  STAGE(0, 0);
  __syncthreads();

  for (int k0 = 0; k0 < K_DIM; k0 += 2 * BK) {
    STAGE(k0 + BK, 1);
    COMPUTE(0);
    __syncthreads();
    if (k0 + 2 * BK < K_DIM) STAGE(k0 + 2 * BK, 0);
    COMPUTE(1);
    __syncthreads();
  }

#undef STAGE
#undef COMPUTE

  // ---- Epilogue phase 1: pack acc -> smem in pk-record image -------------
  const int seg = n0 >> 10;        // 0=k 1=v 2=q (uniform per block)
  const int pq = quad >> 1;
  const int jq8 = (l15 & 7) * 8;
#pragma unroll
  for (int ni = 0; ni < 4; ni++) {
    const int nbl = (wn * 64 + ni * 16 + l15) >> 3;
#pragma unroll
    for (int r = 0; r < 4; r++) {
      const int bq = (quad * 4 + r) & 7;
      float w0 = acc[0][ni][r], w1 = acc[1][ni][r];
      float w2 = acc[2][ni][r], w3 = acc[3][ni][r];
      if (seg == 0) {  // wave-uniform: normalize each k-row over its 8 j-lanes
        float s0 = reduce8(w0 * w0), s1 = reduce8(w1 * w1);
        float s2 = reduce8(w2 * w2), s3 = reduce8(w3 * w3);
        w0 *= __builtin_amdgcn_rcpf(__builtin_amdgcn_sqrtf(s0) + 1e-6f);
        w1 *= __builtin_amdgcn_rcpf(__builtin_amdgcn_sqrtf(s1) + 1e-6f);
        w2 *= __builtin_amdgcn_rcpf(__builtin_amdgcn_sqrtf(s2) + 1e-6f);
        w3 *= __builtin_amdgcn_rcpf(__builtin_amdgcn_sqrtf(s3) + 1e-6f);
      }
      uint2 pr;
      pr.x = (unsigned)f2bf(w0) | ((unsigned)f2bf(w1) << 16);
      pr.y = (unsigned)f2bf(w2) | ((unsigned)f2bf(w3) << 16);
      const int idx = ((wm * 8 + bq) * 16 + nbl) * 64 + jq8 + pq * 4;
      *(uint2*)(smem + idx) = pr;  // 8-B aligned ds_write_b64
    }
  }
  __syncthreads();

  // ---- Epilogue phase 2: linear LDS read -> 128-B-coalesced pk stores ----
  const int tblk0 = m0 >> 6;          // mTile*2
  const int nbq0 = (n0 & 1023) >> 3;
#pragma unroll
  for (int it = 0; it < 8; it++) {
    const int chunk = it * 256 + tid;       // 0..2047, 16 B each
    const int jqc = chunk & 7;
    const int nblc = (chunk >> 3) & 15;
    const int bqc = (chunk >> 7) & 7;
    const int wmc = chunk >> 10;            // 0..1
    uintx4 d = *(const uintx4*)(smem + chunk * 8);
    const size_t addr = (size_t)(bqc * NB + nbq0 + nblc) * C_PLANE +
                        (size_t)(tblk0 + wmc) * 192 + seg * 64 + jqc * 8;
    *(uintx4*)(pk + addr) = d;
  }
}

// ---------------- Kernel 3: scan, E=2 quad-rows + Pade(5,4) tanh -----------
// R8 proved the wall is the per-row dependency chain (TLP/ILP/prefetch all
// null; 1024 serial chains on 1024 SIMDs -> only chain-shortening helps).
// E=2: lane = (i<<2)|h holds S[i][2h],S[i][2h+1]; row = one QUAD. Reduce =
// in-lane pair-fma + 2 quad_perm DPPs (drops the 3rd, cross-quad DPP level).
// tanh via Pade(5,4) [Gauss CF]: tanh(x) ~= x(945+105r+r^2)/(945+420r+15r^2),
// r = x^2, clamp |x|<=3.75 (err <= ~1e-3, same order as bf16 pk noise).
// Kills the serial exp2->add->rcp: ONE rcp remains, x*NUM runs parallel to
// it. Shadow-T state eliminated. Lanes 32-63 duplicate rows (stores masked).
#define C_LOG2E  1.4426950408889634f
#define TCLAMP   3.75f

__global__ __launch_bounds__(64, 1) void scan_kernel(
    const unsigned short* __restrict__ pk, float* __restrict__ out) {
  const int chain = blockIdx.x;        // b*128+nb
  const int b = chain >> 7, nb = chain & 127;
  const int lane = (int)threadIdx.x & 31;   // upper half duplicates
  const int i = lane >> 2, h = lane & 3;
  const bool writer = (threadIdx.x < 32);

  const unsigned short* pc = pk + (size_t)chain * C_PLANE;
  const int k0off = h * 16, k1off = h * 16 + 8;
  const int voff = 64 + i * 8;
  const int q0off = 128 + h * 16, q1off = 128 + h * 16 + 8;

  float S0 = 0.f, S1 = 0.f, zA = 0.f, zB = 0.f;
  float* outA = out + (size_t)h * (B_DIM * NSTATE) + b * NSTATE + nb * BLKSZ + i;
  float* outB = outA + (size_t)4 * (B_DIM * NSTATE);

#define RELOAD(RK0, RK1, RV, RQ0, RQ1, TNEXT)               \
  {                                                         \
    const unsigned short* rec = pc + (size_t)(TNEXT) * 192; \
    RK0 = *(const uintx4*)(rec + k0off);                    \
    RK1 = *(const uintx4*)(rec + k1off);                    \
    RV  = *(const uintx4*)(rec + voff);                     \
    RQ0 = *(const uintx4*)(rec + q0off);                    \
    RQ1 = *(const uintx4*)(rec + q1off);                    \
  }

#define CONSUME(RK0, RK1, RV, RQ0, RQ1)                                     \
  {                                                                         \
    _Pragma("unroll") for (int u = 0; u < 8; u++) {                         \
      const int s = ((u & 1) << 2) | (u >> 1);  /* ut_store of step u */    \
      float k0 = bfu(RK0[s >> 1], s & 1);                                   \
      float k1 = bfu(RK1[s >> 1], s & 1);                                   \
      float vv = bfu(RV[s >> 1], s & 1);                                    \
      float q0 = bfu(RQ0[s >> 1], s & 1);                                   \
      float q1 = bfu(RQ1[s >> 1], s & 1);                                   \
      float base0 = fmaf(vv, k0, S0);      /* parallel with pp chain */     \
      float base1 = fmaf(vv, k1, S1);                                       \
      float pp = fmaf(S1, k1, S0 * k0);    /* in-lane pair dot */           \
      pp = dpp_add<0xB1>(pp);              /* + lane^1 (quad_perm) */       \
      pp = dpp_add<0x4E>(pp);              /* + lane^2 -> row sum p */      \
      float x0 = fmaf(-pp, k0, base0);     /* = S + (v-p)*k */              \
      float x1 = fmaf(-pp, k1, base1);                                      \
      x0 = fmaxf(-TCLAMP, fminf(TCLAMP, x0));  /* v_med3 */                 \
      x1 = fmaxf(-TCLAMP, fminf(TCLAMP, x1));                               \
      float r0 = x0 * x0, r1 = x1 * x1;                                     \
      float n0 = fmaf(r0, r0 + 105.f, 945.f);                               \
      float n1 = fmaf(r1, r1 + 105.f, 945.f);                               \
      float d0 = fmaf(r0, fmaf(r0, 15.f, 420.f), 945.f);                    \
      float d1 = fmaf(r1, fmaf(r1, 15.f, 420.f), 945.f);                    \
      float rd0 = __builtin_amdgcn_rcpf(d0);                                \
      float rd1 = __builtin_amdgcn_rcpf(d1);                                \
      float xn0 = x0 * n0, xn1 = x1 * n1;  /* parallel with rcp */          \
      S0 = xn0 * rd0;                                                       \
      S1 = xn1 * rd1;                                                       \
      float zp = fmaf(S1, q1, S0 * q0);                                     \
      zp = dpp_add<0xB1>(zp);                                               \
      zp = dpp_add<0x4E>(zp);              /* z in all 4 row lanes */       \
      if (u < 4) zA = (h == u) ? zp : zA;                                   \
      else       zB = (h == u - 4) ? zp : zB;                               \
    }                                                                       \
    /* per-tblk epilogue: 2 sigmoids + 2 coalesced stores (masked) */       \
    float sgA = __builtin_amdgcn_rcpf(                                      \
        1.f + __builtin_amdgcn_exp2f(zA * -C_LOG2E));                       \
    float sgB = __builtin_amdgcn_rcpf(                                      \
        1.f + __builtin_amdgcn_exp2f(zB * -C_LOG2E));                       \
    if (writer) {                                                           \
      *outA = zA * zA * sgA;                                                \
      *outB = zB * zB * sgB;                                                \
    }                                                                       \
    outA += 8 * (B_DIM * NSTATE);                                           \
    outB += 8 * (B_DIM * NSTATE);                                           \
  }

  uintx4 ak0, ak1, av, aq0, aq1;
  uintx4 bk0, bk1, bv, bq0, bq1;
  uintx4 ck0, ck1, cv, cq0, cq1;
  RELOAD(ak0, ak1, av, aq0, aq1, 0);
  RELOAD(bk0, bk1, bv, bq0, bq1, 1);
  RELOAD(ck0, ck1, cv, cq0, cq1, 2);
  __builtin_amdgcn_sched_barrier(0);

  // 255 = 85*3 tblks in the pipelined loop; tblk 255 is the drain tail.
  for (int tb = 0; tb < 255; tb += 3) {
    CONSUME(ak0, ak1, av, aq0, aq1);
    RELOAD(ak0, ak1, av, aq0, aq1, tb + 3);
    __builtin_amdgcn_sched_barrier(0);
    CONSUME(bk0, bk1, bv, bq0, bq1);
    RELOAD(bk0, bk1, bv, bq0, bq1, (tb + 4 < 256) ? tb + 4 : 255);
    __builtin_amdgcn_sched_barrier(0);
    CONSUME(ck0, ck1, cv, cq0, cq1);
    RELOAD(ck0, ck1, cv, cq0, cq1, (tb + 5 < 256) ? tb + 5 : 255);
    __builtin_amdgcn_sched_barrier(0);
  }
  CONSUME(ak0, ak1, av, aq0, aq1);

#undef RELOAD
#undef CONSUME

  // S_final: [B][NB][8][8]; lane (i,h) -> elements i*8+2h, i*8+2h+1
  if (writer) {
    *(float2*)(out + (size_t)T_DIM * B_DIM * NSTATE + (size_t)chain * 64 +
               i * 8 + 2 * h) = make_float2(S0, S1);
  }
}

// ---------------- launch ---------------------------------------------------
extern "C" void kernel_launch(void* const* d_in, const int* in_sizes, int n_in,
                              void* d_out, int out_size, void* d_ws,
                              size_t ws_size, hipStream_t stream) {
  const float* x = (const float*)d_in[0];
  const float* Wk = (const float*)d_in[1];
  const float* Wv = (const float*)d_in[2];
  const float* Wq = (const float*)d_in[3];
  float* out = (float*)d_out;

  unsigned short* xb = (unsigned short*)d_ws;                  // 32 MiB
  unsigned short* wb = xb + (size_t)M_DIM * K_DIM;             // 6 MiB
  unsigned short* pk = wb + (size_t)N_DIM * K_DIM;             // 96 MiB packed

  convert_kernel<<<M_DIM + N_DIM, 256, 0, stream>>>(x, Wk, Wv, Wq, xb, wb);
  gemm_kernel<<<(M_DIM / BM) * (N_DIM / BN), 256, 0, stream>>>(xb, wb, pk);
  scan_kernel<<<B_DIM * NB, 64, 0, stream>>>(pk, out);
}